// Round 14
// baseline (123.794 us; speedup 1.0000x reference)
//
#include <hip/hip_runtime.h>
#include <math.h>

// SSIM (16,3,512,512) fp32, 11x11 separable Gaussian, VALID -> per-batch mean [16].
//
// Round-14: stateless two-phase design (no per-thread ring -> no AGPR split).
//  Phase A: H-pass. Thread computes 4-channel windowed sums {r,d,rr+dd,rd}
//    for ~8 (row,col) cells, loading its 11-float windows directly from
//    global (unaligned dwordx4, L1 absorbs overlap), writes float4 to LDS
//    hb[col][row] (col-major, stride 35 float4 = 4*odd dwords -> bank-minimal).
//  Phase B: V-pass. Thread owns 6 consecutive output rows of one column:
//    streams 16 LDS float4, scatters into 6 accumulator sets (2.7 reads/out),
//    SSIM, block reduction, one atomicAdd.
//  Tile: 64 cols x 24 out-rows (34 input rows). LDS 35.9 KB -> 4 blocks/CU.
//  One barrier per block. No inline asm, no global_load_lds.
//  255x scaling cancels: C1 = 1e-4, C2 = 9e-4 on [0,1] data.

#define WSZ 11
#define IMG 512
#define OSZ 502
#define NT  256
#define TH  24           // output rows per tile
#define IR  34           // input rows per tile (TH + 10)
#define STR 35           // f4 stride per column (>= IR, 4*odd dwords)
#define NCH 21           // ceil(502/24)

struct WinArg { float w[WSZ]; };

typedef float f4 __attribute__((ext_vector_type(4)));

#define C1V 1.0e-4f
#define C2V 9.0e-4f

__device__ __forceinline__ f4 ld4(const float* p) {
    f4 v;
    __builtin_memcpy(&v, p, 16);   // <4 x float>, align 4 -> global_load_dwordx4
    return v;
}

// element e (0..10) of the 11-float window held in A(+0), B(+4), C(+7)
#define EL(A_, B_, C_, E) ((E) < 4 ? (A_)[(E)] : ((E) < 8 ? (B_)[(E) - 4] : (C_)[(E) - 7]))

__global__ __launch_bounds__(NT, 4) void ssim_2ph(
    const float* __restrict__ rawp, const float* __restrict__ dstp,
    float* __restrict__ out, WinArg wa, float inv_n)
{
    __shared__ f4 hb[64 * STR];      // 35840 B, col-major [col][row]
    __shared__ float wred[NT / 64];

    const int tid  = threadIdx.x;
    const int lane = tid & 63;
    const int wave = tid >> 6;
    const int rc    = blockIdx.x;    // row chunk
    const int strip = blockIdx.y;    // 64-col strip (0..7)
    const int img   = blockIdx.z;

    const int o0 = rc * TH;          // first output row of tile
    const int cb = strip * 64;       // first column of tile

    const size_t ibase = (size_t)img * (size_t)(IMG * IMG);

    // ================= Phase A: horizontal pass =================
    {
        const int col  = lane;                       // 0..63 within strip
        const int hcol = min(cb + col, OSZ - 1);     // clamp: window stays in-bounds
        const float* rbase = rawp + ibase + (size_t)hcol;
        const float* dbase = dstp + ibase + (size_t)hcol;

#pragma unroll
        for (int i = 0; i < 9; ++i) {
            const int r = wave + 4 * i;              // 0..35, wave-uniform guard
            if (r < IR) {
                const int gr = min(o0 + r, IMG - 1); // clamp tail rows
                const float* rp = rbase + (size_t)gr * IMG;
                const float* dp = dbase + (size_t)gr * IMG;
                const f4 A = ld4(rp);     const f4 B = ld4(rp + 4);
                const f4 C = ld4(rp + 7);
                const f4 D = ld4(dp);     const f4 E = ld4(dp + 4);
                const f4 F = ld4(dp + 7);

                float s1 = 0.f, s2 = 0.f, s3 = 0.f, s4 = 0.f;
#pragma unroll
                for (int e = 0; e < WSZ; ++e) {
                    const float r_ = EL(A, B, C, e);
                    const float d_ = EL(D, E, F, e);
                    const float w_ = wa.w[e];
                    s1 = fmaf(w_, r_, s1);
                    s2 = fmaf(w_, d_, s2);
                    s3 = fmaf(w_, fmaf(d_, d_, r_ * r_), s3);
                    s4 = fmaf(w_, r_ * d_, s4);
                }
                f4 hv; hv[0] = s1; hv[1] = s2; hv[2] = s3; hv[3] = s4;
                hb[col * STR + r] = hv;
            }
        }
    }
    __syncthreads();

    // ================= Phase B: vertical pass + SSIM =================
    float acc = 0.0f;
    {
        const int col  = lane;
        const int gout = cb + col;                   // output column
        const bool cok = (gout < OSZ);
        const int rb   = wave * 6;                   // first local output row

        float m[6][4];
#pragma unroll
        for (int m_ = 0; m_ < 6; ++m_)
#pragma unroll
            for (int ch = 0; ch < 4; ++ch) m[m_][ch] = 0.f;

#pragma unroll
        for (int j = 0; j < 16; ++j) {               // local input rows rb..rb+15
            const f4 h = hb[col * STR + rb + j];
#pragma unroll
            for (int m_ = 0; m_ < 6; ++m_) {
                const int tap = j - m_;              // static
                if (tap >= 0 && tap < WSZ) {
                    const float w_ = wa.w[tap];
                    m[m_][0] = fmaf(w_, h[0], m[m_][0]);
                    m[m_][1] = fmaf(w_, h[1], m[m_][1]);
                    m[m_][2] = fmaf(w_, h[2], m[m_][2]);
                    m[m_][3] = fmaf(w_, h[3], m[m_][3]);
                }
            }
        }

#pragma unroll
        for (int m_ = 0; m_ < 6; ++m_) {
            const int orow = o0 + rb + m_;
            if (cok && orow < OSZ) {
                const float m1 = m[m_][0], m2 = m[m_][1];
                const float m3 = m[m_][2], m4 = m[m_][3];
                const float q1 = m1 * m1, q2 = m2 * m2, mm = m1 * m2;
                const float num = (2.f * mm + C1V) * (2.f * (m4 - mm) + C2V);
                const float den = (q1 + q2 + C1V) * (((m3 - q1) - q2) + C2V);
                acc += num * __builtin_amdgcn_rcpf(den);
            }
        }
    }

    // ---- block reduction -> one atomicAdd per block ----
#pragma unroll
    for (int off = 32; off > 0; off >>= 1) acc += __shfl_down(acc, off, 64);
    if (lane == 0) wred[wave] = acc;
    __syncthreads();
    if (tid == 0) {
        const float tot = (wred[0] + wred[1]) + (wred[2] + wred[3]);
        atomicAdd(out + img / 3, tot * inv_n);
    }
}

extern "C" void kernel_launch(void* const* d_in, const int* in_sizes, int n_in,
                              void* d_out, int out_size, void* d_ws, size_t ws_size,
                              hipStream_t stream) {
    const float* raw = (const float*)d_in[0];
    const float* dst = (const float*)d_in[1];
    float* out = (float*)d_out;

    hipMemsetAsync(out, 0, (size_t)out_size * sizeof(float), stream);

    WinArg wa;
    double g[WSZ], s = 0.0;
    for (int i = 0; i < WSZ; ++i) {
        double ax = (double)i - (double)(WSZ - 1) / 2.0;
        g[i] = exp(-(ax * ax) / (2.0 * 1.5 * 1.5));
        s += g[i];
    }
    for (int i = 0; i < WSZ; ++i) wa.w[i] = (float)(g[i] / s);

    const float inv_n = (float)(1.0 / (3.0 * (double)OSZ * (double)OSZ));

    dim3 grid(NCH, 8, 48);
    ssim_2ph<<<grid, NT, 0, stream>>>(raw, dst, out, wa, inv_n);
}

// Round 15
// 66.558 us; speedup vs baseline: 1.8599x; 1.8599x over previous
//
#include <hip/hip_runtime.h>
#include <math.h>

// SSIM (16,3,512,512) fp32, 11x11 separable Gaussian, VALID -> per-batch mean [16].
//
// Round-15: EXACT round-12 structure (best: 76.9us), with the inner math
// converted to packed fp32 (v_pk_fma_f32 / v_pk_mul_f32, VOP3P).
// MI355X's 157.3 TF fp32 is the PACKED rate; scalar v_fma_f32 is 78.6 TF.
// The channel-interleaved LDS layout float4(r,d,r,d) makes (r,d) an adjacent
// VGPR pair, so {mu_r,mu_d} and {E[r^2+d^2],E[rd]} accumulate as f32x2 pairs:
// 88 scalar fma/row -> 44 pk_fma (H-pass), 88 -> 44 (V-pass). Inline asm
// guarantees VOP3P emission; per-lane IEEE fma semantics are unchanged.
//  - Each wave owns a 128-output-col strip (2 cols/thread) and stages its own
//    rows via global_load_lds; per-wave vmcnt(24) is the only synchronization.
//  - 255x scaling cancels: C1 = 1e-4, C2 = 9e-4 on [0,1] data.

#define WSZ 11
#define IMG 512
#define OSZ 502
#define NT  256
#define CH_OUT 32
#define NCHUNK 16        // 16*32 >= 502
#define NSLOT 11
#define LA 6             // lookahead rows

struct WinArg { float w[WSZ]; };

typedef float f2 __attribute__((ext_vector_type(2)));
typedef float f4v __attribute__((ext_vector_type(4)));

typedef const __attribute__((address_space(1))) unsigned int* gp_t;
typedef __attribute__((address_space(3))) unsigned int* sp_t;

#define C1V 1.0e-4f
#define C2V 9.0e-4f

__device__ __forceinline__ void pkfma(f2& acc, f2 a, f2 b) {
    asm("v_pk_fma_f32 %0, %1, %2, %0" : "+v"(acc) : "v"(a), "v"(b));
}
__device__ __forceinline__ f2 pkmul(f2 a, f2 b) {
    f2 r;
    asm("v_pk_mul_f32 %0, %1, %2" : "=v"(r) : "v"(a), "v"(b));
    return r;
}

__global__ __launch_bounds__(NT, 2) void ssim_pk(
    const float* __restrict__ rawp, const float* __restrict__ dstp,
    float* __restrict__ out, WinArg wa, float inv_n)
{
    // waves 0-2: 11 slots x 80 float4 (880 f4 each); wave 3: 11 x 64 (704 f4)
    __shared__ f4v srow[3344];               // 53504 B
    __shared__ float wred[NT / 64];

    const int tid  = threadIdx.x;
    const int lane = tid & 63;
    const int wave = tid >> 6;
    const int chunk = blockIdx.x;
    const int img   = blockIdx.y;

    const int o0    = chunk * CH_OUT;
    const int olim  = min(o0 + CH_OUT, OSZ);
    const int rlast = min(o0 + CH_OUT + WSZ - 2, IMG - 1);
    const int NR    = rlast - o0 + 1;        // 42 (32 for last chunk)

    const bool w3     = (wave == 3);
    const int  nch    = w3 ? 4 : 5;          // DMA chunks per row (wave-uniform)
    const int  slotf4 = w3 ? 64 : 80;        // float4 per slot (wave-uniform)
    f4v* region = srow + wave * 880;         // wave 3 -> 2640, uses 704 f4
    const int  rl     = (w3 && lane > 58) ? 58 : lane;   // read clamp
    const bool active = !(w3 && lane > 58);

    const size_t ibase = (size_t)img * (size_t)(IMG * IMG);
    // lane parity -> channel; (lane>>1) -> col within 32-col chunk
    const float* lane_base = ((lane & 1) ? dstp : rawp) + ibase
                           + (size_t)(wave * 128 + (lane >> 1));

    // duplicated weights for packed ops (loop-invariant, hoisted)
    f2 wv[WSZ];
#pragma unroll
    for (int j = 0; j < WSZ; ++j) { wv[j].x = wa.w[j]; wv[j].y = wa.w[j]; }

#define STAGE(ROW, SLOT)                                                       \
    {                                                                          \
        const float* _s = lane_base + (size_t)(ROW) * IMG;                     \
        float* _d = (float*)(region + (SLOT) * slotf4);                        \
        _Pragma("unroll")                                                      \
        for (int _c = 0; _c < 5; ++_c) {                                       \
            if (_c < nch)                                                      \
                __builtin_amdgcn_global_load_lds(                              \
                    (gp_t)(const void*)(_s + 32 * _c),                         \
                    (sp_t)(void*)(_d + 64 * _c), 4, 0, 0);                     \
        }                                                                      \
    }

    f2 hs12[WSZ][2];                         // ring: [slot][col] {mu_r, mu_d}
    f2 hs34[WSZ][2];                         // ring: [slot][col] {E_rr+dd, E_rd}
    float acc = 0.0f;

    // prologue: rows 0..LA-1 in flight (slots 0..5)
#pragma unroll
    for (int r = 0; r < LA; ++r) STAGE(o0 + r, r)

#pragma unroll 1
    for (int rr = 0; rr < NR; rr += WSZ) {
#pragma unroll
        for (int k = 0; k < WSZ; ++k) {
            const int klin = rr + k;
            if (klin < NR) {                 // block-uniform
                // stage row klin+LA (clamped tail restage lands in dead slot)
                {
                    int rs = klin + LA; if (rs > NR - 1) rs = NR - 1;
                    STAGE(o0 + rs, (k + LA) % NSLOT)
                }
                // per-wave wait: guarantees row klin's loads complete
                asm volatile("s_waitcnt vmcnt(24)" ::: "memory");

                f4v q[6];
                {
                    const f4v* rp = region + k * slotf4 + rl;
#pragma unroll
                    for (int j = 0; j < 6; ++j) q[j] = rp[j];
                }

                // ---- H-pass, 2 cols, packed channels ----
                f2 s12a = {0.f, 0.f}, s34a = {0.f, 0.f};
                f2 s12b = {0.f, 0.f}, s34b = {0.f, 0.f};
#pragma unroll
                for (int e = 0; e < 12; ++e) {
                    const f2 rd = (e & 1) ? q[e >> 1].zw : q[e >> 1].xy;
                    const f2 rr2 = pkmul(rd, rd);          // (r^2, d^2)
                    f2 sp;                                  // (r^2+d^2, r*d)
                    sp.x = rr2.x + rr2.y;
                    sp.y = rd.x * rd.y;
                    if (e < 11) {            // col a tap e
                        pkfma(s12a, wv[e], rd);
                        pkfma(s34a, wv[e], sp);
                    }
                    if (e >= 1) {            // col b tap e-1
                        pkfma(s12b, wv[e - 1], rd);
                        pkfma(s34b, wv[e - 1], sp);
                    }
                }
                hs12[k][0] = s12a; hs34[k][0] = s34a;
                hs12[k][1] = s12b; hs34[k][1] = s34b;

                // ---- V-pass + SSIM ----
                const int o = o0 + klin - (WSZ - 1);
                if (klin >= WSZ - 1 && o < olim && active) {
                    f2 m12a = {0.f, 0.f}, m34a = {0.f, 0.f};
                    f2 m12b = {0.f, 0.f}, m34b = {0.f, 0.f};
#pragma unroll
                    for (int i = 0; i < WSZ; ++i) {
                        const int s = (k + 1 + i) % WSZ;   // static after unroll
                        pkfma(m12a, wv[i], hs12[s][0]);
                        pkfma(m34a, wv[i], hs34[s][0]);
                        pkfma(m12b, wv[i], hs12[s][1]);
                        pkfma(m34b, wv[i], hs34[s][1]);
                    }
                    {
                        const float m1 = m12a.x, m2 = m12a.y;
                        const float m3 = m34a.x, m4 = m34a.y;
                        const float q1 = m1 * m1, q2 = m2 * m2, mm = m1 * m2;
                        const float num = (2.f * mm + C1V) * (2.f * (m4 - mm) + C2V);
                        const float den = (q1 + q2 + C1V) * (((m3 - q1) - q2) + C2V);
                        acc += num * __builtin_amdgcn_rcpf(den);
                    }
                    {
                        const float m1 = m12b.x, m2 = m12b.y;
                        const float m3 = m34b.x, m4 = m34b.y;
                        const float q1 = m1 * m1, q2 = m2 * m2, mm = m1 * m2;
                        const float num = (2.f * mm + C1V) * (2.f * (m4 - mm) + C2V);
                        const float den = (q1 + q2 + C1V) * (((m3 - q1) - q2) + C2V);
                        acc += num * __builtin_amdgcn_rcpf(den);
                    }
                }
            }
        }
    }
#undef STAGE

    // ---- block reduction -> one atomicAdd per block ----
#pragma unroll
    for (int off = 32; off > 0; off >>= 1) acc += __shfl_down(acc, off, 64);
    if (lane == 0) wred[wave] = acc;
    __syncthreads();
    if (tid == 0) {
        const float tot = (wred[0] + wred[1]) + (wred[2] + wred[3]);
        atomicAdd(out + img / 3, tot * inv_n);
    }
}

extern "C" void kernel_launch(void* const* d_in, const int* in_sizes, int n_in,
                              void* d_out, int out_size, void* d_ws, size_t ws_size,
                              hipStream_t stream) {
    const float* raw = (const float*)d_in[0];
    const float* dst = (const float*)d_in[1];
    float* out = (float*)d_out;

    hipMemsetAsync(out, 0, (size_t)out_size * sizeof(float), stream);

    WinArg wa;
    double g[WSZ], s = 0.0;
    for (int i = 0; i < WSZ; ++i) {
        double ax = (double)i - (double)(WSZ - 1) / 2.0;
        g[i] = exp(-(ax * ax) / (2.0 * 1.5 * 1.5));
        s += g[i];
    }
    for (int i = 0; i < WSZ; ++i) wa.w[i] = (float)(g[i] / s);

    const float inv_n = (float)(1.0 / (3.0 * (double)OSZ * (double)OSZ));

    dim3 grid(NCHUNK, 48);
    ssim_pk<<<grid, NT, 0, stream>>>(raw, dst, out, wa, inv_n);
}

// Round 16
// 59.386 us; speedup vs baseline: 2.0846x; 1.1208x over previous
//
#include <hip/hip_runtime.h>
#include <math.h>

// SSIM (16,3,512,512) fp32, 11x11 separable Gaussian, VALID -> per-batch mean [16].
//
// Round-16: round-15 structure (66.6us) with:
//  1) packed math via native float2 ops (__builtin_elementwise_fma -> 
//     v_pk_fma_f32 by ISel) instead of inline asm -- the asm "v" constraints
//     forced AGPR->VGPR copies around every ring access; native ops let the
//     allocator use the unified file freely with no constraint copies.
//  2) __launch_bounds__(256,3): 170-reg budget, LDS 53.8KB x3 = 161KB fits
//     -> 3 blocks/CU = 12 waves/CU (37.5% ceiling, was hard-capped at 25%).
//  - Each wave owns a 128-output-col strip (2 cols/thread) and stages its own
//    rows via global_load_lds; per-wave vmcnt(24) is the only synchronization.
//  - Channel-interleaved LDS float4(r,d,r,d); {mu_r,mu_d} and {E_rr+dd,E_rd}
//    accumulate as f32x2 pairs: 44 pk_fma per row per pass.
//  - 255x scaling cancels: C1 = 1e-4, C2 = 9e-4 on [0,1] data.

#define WSZ 11
#define IMG 512
#define OSZ 502
#define NT  256
#define CH_OUT 32
#define NCHUNK 16        // 16*32 >= 502
#define NSLOT 11
#define LA 6             // lookahead rows

struct WinArg { float w[WSZ]; };

typedef float f2 __attribute__((ext_vector_type(2)));
typedef float f4v __attribute__((ext_vector_type(4)));

typedef const __attribute__((address_space(1))) unsigned int* gp_t;
typedef __attribute__((address_space(3))) unsigned int* sp_t;

#define C1V 1.0e-4f
#define C2V 9.0e-4f

__device__ __forceinline__ void pkfma(f2& acc, f2 a, f2 b) {
    acc = __builtin_elementwise_fma(a, b, acc);   // v_pk_fma_f32
}

__global__ __launch_bounds__(NT, 3) void ssim_pk3(
    const float* __restrict__ rawp, const float* __restrict__ dstp,
    float* __restrict__ out, WinArg wa, float inv_n)
{
    // waves 0-2: 11 slots x 80 float4 (880 f4 each); wave 3: 11 x 64 (704 f4)
    __shared__ f4v srow[3344];               // 53504 B
    __shared__ float wred[NT / 64];

    const int tid  = threadIdx.x;
    const int lane = tid & 63;
    const int wave = tid >> 6;
    const int chunk = blockIdx.x;
    const int img   = blockIdx.y;

    const int o0    = chunk * CH_OUT;
    const int olim  = min(o0 + CH_OUT, OSZ);
    const int rlast = min(o0 + CH_OUT + WSZ - 2, IMG - 1);
    const int NR    = rlast - o0 + 1;        // 42 (32 for last chunk)

    const bool w3     = (wave == 3);
    const int  nch    = w3 ? 4 : 5;          // DMA chunks per row (wave-uniform)
    const int  slotf4 = w3 ? 64 : 80;        // float4 per slot (wave-uniform)
    f4v* region = srow + wave * 880;         // wave 3 -> 2640, uses 704 f4
    const int  rl     = (w3 && lane > 58) ? 58 : lane;   // read clamp
    const bool active = !(w3 && lane > 58);

    const size_t ibase = (size_t)img * (size_t)(IMG * IMG);
    // lane parity -> channel; (lane>>1) -> col within 32-col chunk
    const float* lane_base = ((lane & 1) ? dstp : rawp) + ibase
                           + (size_t)(wave * 128 + (lane >> 1));

    // packed weights (compiler hoists / rematerializes as it prefers)
    f2 wv[WSZ];
#pragma unroll
    for (int j = 0; j < WSZ; ++j) { wv[j].x = wa.w[j]; wv[j].y = wa.w[j]; }

#define STAGE(ROW, SLOT)                                                       \
    {                                                                          \
        const float* _s = lane_base + (size_t)(ROW) * IMG;                     \
        float* _d = (float*)(region + (SLOT) * slotf4);                        \
        _Pragma("unroll")                                                      \
        for (int _c = 0; _c < 5; ++_c) {                                       \
            if (_c < nch)                                                      \
                __builtin_amdgcn_global_load_lds(                              \
                    (gp_t)(const void*)(_s + 32 * _c),                         \
                    (sp_t)(void*)(_d + 64 * _c), 4, 0, 0);                     \
        }                                                                      \
    }

    f2 hs12[WSZ][2];                         // ring: [slot][col] {mu_r, mu_d}
    f2 hs34[WSZ][2];                         // ring: [slot][col] {E_rr+dd, E_rd}
    float acc = 0.0f;

    // prologue: rows 0..LA-1 in flight (slots 0..5)
#pragma unroll
    for (int r = 0; r < LA; ++r) STAGE(o0 + r, r)

#pragma unroll 1
    for (int rr = 0; rr < NR; rr += WSZ) {
#pragma unroll
        for (int k = 0; k < WSZ; ++k) {
            const int klin = rr + k;
            if (klin < NR) {                 // block-uniform
                // stage row klin+LA (clamped tail restage lands in dead slot)
                {
                    int rs = klin + LA; if (rs > NR - 1) rs = NR - 1;
                    STAGE(o0 + rs, (k + LA) % NSLOT)
                }
                // per-wave wait: guarantees row klin's loads complete
                asm volatile("s_waitcnt vmcnt(24)" ::: "memory");

                f4v q[6];
                {
                    const f4v* rp = region + k * slotf4 + rl;
#pragma unroll
                    for (int j = 0; j < 6; ++j) q[j] = rp[j];
                }

                // ---- H-pass, 2 cols, packed channels ----
                f2 s12a = {0.f, 0.f}, s34a = {0.f, 0.f};
                f2 s12b = {0.f, 0.f}, s34b = {0.f, 0.f};
#pragma unroll
                for (int e = 0; e < 12; ++e) {
                    const f2 rd = (e & 1) ? q[e >> 1].zw : q[e >> 1].xy;
                    const f2 rr2 = rd * rd;                // v_pk_mul_f32
                    f2 sp;                                 // (r^2+d^2, r*d)
                    sp.x = rr2.x + rr2.y;
                    sp.y = rd.x * rd.y;
                    if (e < 11) {            // col a tap e
                        pkfma(s12a, wv[e], rd);
                        pkfma(s34a, wv[e], sp);
                    }
                    if (e >= 1) {            // col b tap e-1
                        pkfma(s12b, wv[e - 1], rd);
                        pkfma(s34b, wv[e - 1], sp);
                    }
                }
                hs12[k][0] = s12a; hs34[k][0] = s34a;
                hs12[k][1] = s12b; hs34[k][1] = s34b;

                // ---- V-pass + SSIM ----
                const int o = o0 + klin - (WSZ - 1);
                if (klin >= WSZ - 1 && o < olim && active) {
                    f2 m12a = {0.f, 0.f}, m34a = {0.f, 0.f};
                    f2 m12b = {0.f, 0.f}, m34b = {0.f, 0.f};
#pragma unroll
                    for (int i = 0; i < WSZ; ++i) {
                        const int s = (k + 1 + i) % WSZ;   // static after unroll
                        pkfma(m12a, wv[i], hs12[s][0]);
                        pkfma(m34a, wv[i], hs34[s][0]);
                        pkfma(m12b, wv[i], hs12[s][1]);
                        pkfma(m34b, wv[i], hs34[s][1]);
                    }
                    {
                        const float m1 = m12a.x, m2 = m12a.y;
                        const float m3 = m34a.x, m4 = m34a.y;
                        const float q1 = m1 * m1, q2 = m2 * m2, mm = m1 * m2;
                        const float num = (2.f * mm + C1V) * (2.f * (m4 - mm) + C2V);
                        const float den = (q1 + q2 + C1V) * (((m3 - q1) - q2) + C2V);
                        acc += num * __builtin_amdgcn_rcpf(den);
                    }
                    {
                        const float m1 = m12b.x, m2 = m12b.y;
                        const float m3 = m34b.x, m4 = m34b.y;
                        const float q1 = m1 * m1, q2 = m2 * m2, mm = m1 * m2;
                        const float num = (2.f * mm + C1V) * (2.f * (m4 - mm) + C2V);
                        const float den = (q1 + q2 + C1V) * (((m3 - q1) - q2) + C2V);
                        acc += num * __builtin_amdgcn_rcpf(den);
                    }
                }
            }
        }
    }
#undef STAGE

    // ---- block reduction -> one atomicAdd per block ----
#pragma unroll
    for (int off = 32; off > 0; off >>= 1) acc += __shfl_down(acc, off, 64);
    if (lane == 0) wred[wave] = acc;
    __syncthreads();
    if (tid == 0) {
        const float tot = (wred[0] + wred[1]) + (wred[2] + wred[3]);
        atomicAdd(out + img / 3, tot * inv_n);
    }
}

extern "C" void kernel_launch(void* const* d_in, const int* in_sizes, int n_in,
                              void* d_out, int out_size, void* d_ws, size_t ws_size,
                              hipStream_t stream) {
    const float* raw = (const float*)d_in[0];
    const float* dst = (const float*)d_in[1];
    float* out = (float*)d_out;

    hipMemsetAsync(out, 0, (size_t)out_size * sizeof(float), stream);

    WinArg wa;
    double g[WSZ], s = 0.0;
    for (int i = 0; i < WSZ; ++i) {
        double ax = (double)i - (double)(WSZ - 1) / 2.0;
        g[i] = exp(-(ax * ax) / (2.0 * 1.5 * 1.5));
        s += g[i];
    }
    for (int i = 0; i < WSZ; ++i) wa.w[i] = (float)(g[i] / s);

    const float inv_n = (float)(1.0 / (3.0 * (double)OSZ * (double)OSZ));

    dim3 grid(NCHUNK, 48);
    ssim_pk3<<<grid, NT, 0, stream>>>(raw, dst, out, wa, inv_n);
}